// Round 2
// baseline (1076.832 us; speedup 1.0000x reference)
//
#include <hip/hip_runtime.h>

// ICON loss (registration), D=128 f32 volumes -> scalar f32.
// Structure:
//   k_pack        : interleave 7 gather-source channels into 32B/voxel
//   k_warp_first  : (both dirs) warp Ieps(3ch)+img+lbl via packed gathers;
//                   writes W (float4) + wimg (planar); dice sums reduced
//   k_warp_second : (both dirs) warp W via float4 gathers; MSE vs Ieps reduced
//   k_lncc        : (both pairs) fully fused separable 5-tap Gaussian
//                   (z->LDS, y->LDS, x->reg) + cross/var + mean reduction
//   k_final       : combine partial sums -> loss

#define DSZ 128
#define DD  (DSZ*DSZ)          // 16384
#define NVOX (DSZ*DSZ*DSZ)     // 2097152
#define NBLK (NVOX/256)        // 8192
#define EPSF 1e-5f

// Gaussian kernel, sigma=1, ksize=5
#define KW0 0.054488684549642945f
#define KW1 0.24420134200323337f
#define KW2 0.40261994689424736f
#define KW3 0.24420134200323337f
#define KW4 0.054488684549642945f

__device__ __forceinline__ double warp_red(double v) {
#pragma unroll
  for (int o = 32; o > 0; o >>= 1) v += __shfl_down(v, o, 64);
  return v;
}

__device__ __forceinline__ void block_acc1(double a, double* acc) {
  __shared__ double s[4];
  const int lane = threadIdx.x & 63, wid = threadIdx.x >> 6;
  a = warp_red(a);
  if (lane == 0) s[wid] = a;
  __syncthreads();
  if (threadIdx.x == 0) atomicAdd(acc, s[0] + s[1] + s[2] + s[3]);
}

__device__ __forceinline__ void block_acc3(double a, double b, double c, double* acc) {
  __shared__ double s[3][4];
  const int lane = threadIdx.x & 63, wid = threadIdx.x >> 6;
  a = warp_red(a); b = warp_red(b); c = warp_red(c);
  if (lane == 0) { s[0][wid] = a; s[1][wid] = b; s[2][wid] = c; }
  __syncthreads();
  if (threadIdx.x == 0) {
    atomicAdd(&acc[0], s[0][0] + s[0][1] + s[0][2] + s[0][3]);
    atomicAdd(&acc[1], s[1][0] + s[1][1] + s[1][2] + s[1][3]);
    atomicAdd(&acc[2], s[2][0] + s[2][1] + s[2][2] + s[2][3]);
  }
}

// Pack gather-source channels: S[v] = {n0,n1,n2,imgA | labA,imgB,labB,0}
__global__ void __launch_bounds__(256) k_pack(
    const float* __restrict__ noise, const float* __restrict__ imgA,
    const float* __restrict__ labA, const float* __restrict__ imgB,
    const float* __restrict__ labB, float4* __restrict__ S) {
  const int v = blockIdx.x * 256 + threadIdx.x;
  float4 a, b;
  a.x = noise[v]; a.y = noise[NVOX + v]; a.z = noise[2*NVOX + v]; a.w = imgA[v];
  b.x = labA[v];  b.y = imgB[v];         b.z = labB[v];           b.w = 0.0f;
  S[2*v] = a; S[2*v + 1] = b;
}

// First warp, both directions (blockIdx.y = dir; 0: phi_AB, 1: phi_BA).
//   W    = warp(Ieps, phi)  -> float4 (x,y,z used)
//   wimg = warp(img,  phi)  -> planar (for LNCC)
//   wl   = warp(lbl,  phi)  -> dice sums vs olbl (reduced only)
__global__ void __launch_bounds__(256) k_warp_first(
    const float* __restrict__ phiAB, const float* __restrict__ phiBA,
    const float4* __restrict__ S,
    const float* __restrict__ labA, const float* __restrict__ labB,
    float4* __restrict__ W1, float4* __restrict__ W2,
    float* __restrict__ wA, float* __restrict__ wB,
    double* __restrict__ acc) {
  const int dir = blockIdx.y;
  const float* __restrict__ phi  = dir ? phiBA : phiAB;
  const float* __restrict__ olbl = dir ? labA  : labB;
  float4* __restrict__ W    = dir ? W2 : W1;
  float*  __restrict__ wimg = dir ? wB : wA;
  double* __restrict__ a    = acc + (dir ? 3 : 0);

  const int v = blockIdx.x * 256 + threadIdx.x;
  const float z = (phi[v]          + 1.0f) * 0.5f * 127.0f;
  const float y = (phi[NVOX + v]   + 1.0f) * 0.5f * 127.0f;
  const float x = (phi[2*NVOX + v] + 1.0f) * 0.5f * 127.0f;
  const float zf = floorf(z), yf = floorf(y), xf = floorf(x);
  const int z0 = (int)zf, y0 = (int)yf, x0 = (int)xf;
  const float fz = z - zf, fy = y - yf, fx = x - xf;
  float o0 = 0.f, o1 = 0.f, o2 = 0.f, oi = 0.f, ol = 0.f;
  if (z0 >= -1 && z0 < DSZ && y0 >= -1 && y0 < DSZ && x0 >= -1 && x0 < DSZ) {
#pragma unroll
    for (int dz = 0; dz < 2; dz++) {
      const int zi = z0 + dz;
      const bool vz = (zi >= 0) && (zi < DSZ);
      const int zc = min(max(zi, 0), DSZ - 1);
      const float wz = dz ? fz : 1.0f - fz;
#pragma unroll
      for (int dy = 0; dy < 2; dy++) {
        const int yi = y0 + dy;
        const bool vy = (yi >= 0) && (yi < DSZ);
        const int yc = min(max(yi, 0), DSZ - 1);
        const float wy = dy ? fy : 1.0f - fy;
#pragma unroll
        for (int dx = 0; dx < 2; dx++) {
          const int xi = x0 + dx;
          const bool vx = (xi >= 0) && (xi < DSZ);
          const int xc = min(max(xi, 0), DSZ - 1);
          const float wx = dx ? fx : 1.0f - fx;
          const float w = (vz && vy && vx) ? wz * wy * wx : 0.0f;
          if (w != 0.0f) {
            const int idx = zc * DD + yc * DSZ + xc;
            const float4 s0 = S[2*idx], s1 = S[2*idx + 1];
            const float e0 = (-1.0f + zc * (2.0f/127.0f)) + s0.x * (1.0f/128.0f);
            const float e1 = (-1.0f + yc * (2.0f/127.0f)) + s0.y * (1.0f/128.0f);
            const float e2 = (-1.0f + xc * (2.0f/127.0f)) + s0.z * (1.0f/128.0f);
            o0 += e0 * w; o1 += e1 * w; o2 += e2 * w;
            const float iv = dir ? s1.y : s0.w;   // imgB : imgA
            const float lv = dir ? s1.z : s1.x;   // labB : labA
            oi += iv * w;
            ol += lv * w;
          }
        }
      }
    }
  }
  W[v] = make_float4(o0, o1, o2, 0.0f);
  wimg[v] = oi;
  const float ob = olbl[v];
  block_acc3((double)(ol * ob), (double)ol, (double)ob, a);
}

// Second warp + MSE, both directions (blockIdx.y = dir).
//   dir 0: fwd = warp(W1, phi_BA) -> acc[6];  dir 1: bwd = warp(W2, phi_AB) -> acc[7]
__global__ void __launch_bounds__(256) k_warp_second_mse(
    const float* __restrict__ phiAB, const float* __restrict__ phiBA,
    const float4* __restrict__ W1, const float4* __restrict__ W2,
    const float* __restrict__ noise, double* __restrict__ acc) {
  const int dir = blockIdx.y;
  const float* __restrict__ phi   = dir ? phiAB : phiBA;
  const float4* __restrict__ Wsrc = dir ? W2 : W1;
  double* __restrict__ a = acc + 6 + dir;

  const int v = blockIdx.x * 256 + threadIdx.x;
  const float z = (phi[v]          + 1.0f) * 0.5f * 127.0f;
  const float y = (phi[NVOX + v]   + 1.0f) * 0.5f * 127.0f;
  const float x = (phi[2*NVOX + v] + 1.0f) * 0.5f * 127.0f;
  const float zf = floorf(z), yf = floorf(y), xf = floorf(x);
  const int z0 = (int)zf, y0 = (int)yf, x0 = (int)xf;
  const float fz = z - zf, fy = y - yf, fx = x - xf;
  float f0 = 0.f, f1 = 0.f, f2 = 0.f;
  if (z0 >= -1 && z0 < DSZ && y0 >= -1 && y0 < DSZ && x0 >= -1 && x0 < DSZ) {
#pragma unroll
    for (int dz = 0; dz < 2; dz++) {
      const int zi = z0 + dz;
      const bool vz = (zi >= 0) && (zi < DSZ);
      const int zc = min(max(zi, 0), DSZ - 1);
      const float wz = dz ? fz : 1.0f - fz;
#pragma unroll
      for (int dy = 0; dy < 2; dy++) {
        const int yi = y0 + dy;
        const bool vy = (yi >= 0) && (yi < DSZ);
        const int yc = min(max(yi, 0), DSZ - 1);
        const float wy = dy ? fy : 1.0f - fy;
#pragma unroll
        for (int dx = 0; dx < 2; dx++) {
          const int xi = x0 + dx;
          const bool vx = (xi >= 0) && (xi < DSZ);
          const int xc = min(max(xi, 0), DSZ - 1);
          const float wx = dx ? fx : 1.0f - fx;
          const float w = (vz && vy && vx) ? wz * wy * wx : 0.0f;
          if (w != 0.0f) {
            const float4 s = Wsrc[zc * DD + yc * DSZ + xc];
            f0 += s.x * w; f1 += s.y * w; f2 += s.z * w;
          }
        }
      }
    }
  }
  const int zi = v >> 14, yi = (v >> 7) & 127, xi = v & 127;
  const float e0 = (-1.0f + zi * (2.0f/127.0f)) + noise[v]          * (1.0f/128.0f);
  const float e1 = (-1.0f + yi * (2.0f/127.0f)) + noise[NVOX + v]   * (1.0f/128.0f);
  const float e2 = (-1.0f + xi * (2.0f/127.0f)) + noise[2*NVOX + v] * (1.0f/128.0f);
  const float d0 = e0 - f0, d1 = e1 - f1, d2 = e2 - f2;
  block_acc1((double)(d0*d0) + (double)(d1*d1) + (double)(d2*d2), a);
}

// Fully fused LNCC: per block = one z-slice x 8-row y-tile x full x.
// Stage1: z-blur of {I,J,IJ,II,JJ} (products on the fly) -> LDS zb[5][12][128]
// Stage2: y-blur -> LDS yb[5][8][128]
// Stage3: x-blur + cross/var + mean-reduce.
// blockIdx.y = pair (0: lncc(wA,imgB) -> acc[8], 1: lncc(imgA,wB) -> acc[9])
__global__ void __launch_bounds__(256) k_lncc(
    const float* __restrict__ wA, const float* __restrict__ imgB,
    const float* __restrict__ imgA, const float* __restrict__ wB,
    double* __restrict__ acc) {
  const int pair = blockIdx.y;
  const float* __restrict__ I = pair ? imgA : wA;
  const float* __restrict__ J = pair ? wB : imgB;
  double* __restrict__ a = acc + 8 + pair;

  const int bx = blockIdx.x;           // 0..2047
  const int zi = bx & 127;
  const int y0 = (bx >> 7) * 8;        // 16 y-tiles

  __shared__ float zb[5][12][128];     // 30 KB
  __shared__ float yb[5][8][128];      // 20 KB
  const int t = threadIdx.x;
  const float K[5] = {KW0, KW1, KW2, KW3, KW4};

  // stage 1: z-blur into LDS (rows y0-2 .. y0+9)
  for (int p = t; p < 12 * 128; p += 256) {
    const int r = p >> 7, x = p & 127;
    const int y = y0 + r - 2;
    float a0 = 0.f, a1 = 0.f, a2 = 0.f, a3 = 0.f, a4 = 0.f;
    if (y >= 0 && y < DSZ) {
      const int base = y * DSZ + x;
#pragma unroll
      for (int s = 0; s < 5; s++) {
        const int zz = zi + s - 2;
        if (zz >= 0 && zz < DSZ) {
          const float iv = I[zz * DD + base], jv = J[zz * DD + base];
          const float k = K[s];
          a0 += k * iv; a1 += k * jv; a2 += k * (iv * jv);
          a3 += k * (iv * iv); a4 += k * (jv * jv);
        }
      }
    }
    zb[0][r][x] = a0; zb[1][r][x] = a1; zb[2][r][x] = a2;
    zb[3][r][x] = a3; zb[4][r][x] = a4;
  }
  __syncthreads();

  // stage 2: y-blur into LDS
  for (int p = t; p < 8 * 128; p += 256) {
    const int r = p >> 7, x = p & 127;
#pragma unroll
    for (int c = 0; c < 5; c++) {
      yb[c][r][x] = KW0 * zb[c][r][x] + KW1 * zb[c][r + 1][x] + KW2 * zb[c][r + 2][x]
                  + KW3 * zb[c][r + 3][x] + KW4 * zb[c][r + 4][x];
    }
  }
  __syncthreads();

  // stage 3: x-blur + LNCC value + reduce
  double lsum = 0.0;
  for (int p = t; p < 8 * 128; p += 256) {
    const int r = p >> 7, x = p & 127;
    float b[5];
#pragma unroll
    for (int c = 0; c < 5; c++) {
      float s = 0.f;
#pragma unroll
      for (int u = 0; u < 5; u++) {
        const int xx = x + u - 2;
        if (xx >= 0 && xx < DSZ) s += K[u] * yb[c][r][xx];
      }
      b[c] = s;
    }
    const float cross = b[2] - b[0] * b[1];
    const float varI = fmaxf(b[3] - b[0] * b[0], 0.0f) + EPSF;
    const float varJ = fmaxf(b[4] - b[1] * b[1], 0.0f) + EPSF;
    lsum += (double)(1.0f - cross / sqrtf(varI * varJ));
  }
  block_acc1(lsum, a);
}

// acc: [0..2]=dice AB (inter, sum wlA, sum labB), [3..5]=dice BA
//      [6]=mse fwd, [7]=mse bwd, [8]=lncc1, [9]=lncc2
__global__ void k_final(const double* __restrict__ acc, float* __restrict__ out) {
  const double n1 = (double)NVOX;
  const double n3 = 3.0 * n1;
  const double ic  = acc[6] / n3 + acc[7] / n3;
  const double sim = acc[8] / n1 + acc[9] / n1;
  const double dA = (2.0 * acc[0] + 1e-5) / (acc[1] + acc[2] + 1e-5);
  const double dB = (2.0 * acc[3] + 1e-5) / (acc[4] + acc[5] + 1e-5);
  out[0] = (float)(128.0 * ic + sim + (1.0 - dA) + (1.0 - dB));
}

extern "C" void kernel_launch(void* const* d_in, const int* in_sizes, int n_in,
                              void* d_out, int out_size, void* d_ws, size_t ws_size,
                              hipStream_t stream) {
  (void)in_sizes; (void)n_in; (void)out_size; (void)ws_size;
  const float* phiAB = (const float*)d_in[0];
  const float* phiBA = (const float*)d_in[1];
  const float* imgA  = (const float*)d_in[2];
  const float* imgB  = (const float*)d_in[3];
  const float* labA  = (const float*)d_in[4];
  const float* labB  = (const float*)d_in[5];
  const float* noise = (const float*)d_in[6];
  float* out = (float*)d_out;

  char* ws = (char*)d_ws;
  double* acc = (double*)ws;                    // 256 B reserved
  float4* S  = (float4*)(ws + 256);             // 2*NVOX float4 = 64 MB
  float4* W1 = S + 2 * (size_t)NVOX;            // NVOX float4 = 32 MB
  float4* W2 = W1 + (size_t)NVOX;               // 32 MB
  float*  wA = (float*)(W2 + (size_t)NVOX);     // 8 MB
  float*  wB = wA + NVOX;                       // 8 MB
  // total: 256 B + 144 MB

  hipMemsetAsync(acc, 0, 16 * sizeof(double), stream);

  k_pack<<<NBLK, 256, 0, stream>>>(noise, imgA, labA, imgB, labB, S);

  k_warp_first<<<dim3(NBLK, 2), 256, 0, stream>>>(
      phiAB, phiBA, S, labA, labB, W1, W2, wA, wB, acc);

  k_warp_second_mse<<<dim3(NBLK, 2), 256, 0, stream>>>(
      phiAB, phiBA, W1, W2, noise, acc);

  k_lncc<<<dim3(2048, 2), 256, 0, stream>>>(wA, imgB, imgA, wB, acc);

  k_final<<<1, 1, 0, stream>>>(acc, out);
}

// Round 10
// 1053.481 us; speedup vs baseline: 1.0222x; 1.0222x over previous
//
#include <hip/hip_runtime.h>

// ICON loss (registration), D=128 f32 volumes -> scalar f32.
// R3 (seventh resubmit; rounds 3-9 all hit GPU-acquisition timeouts — this
// source has never been measured): gather kernels restructured for
// memory-level parallelism — all corner loads issued into explicit register
// arrays before any use (round-2's VGPR=20 register starvation serialized
// 8 L2-miss round trips per wave).

#define DSZ 128
#define DD  (DSZ*DSZ)          // 16384
#define NVOX (DSZ*DSZ*DSZ)     // 2097152
#define NBLK (NVOX/256)        // 8192
#define EPSF 1e-5f

// Gaussian kernel, sigma=1, ksize=5
#define KW0 0.054488684549642945f
#define KW1 0.24420134200323337f
#define KW2 0.40261994689424736f
#define KW3 0.24420134200323337f
#define KW4 0.054488684549642945f

__device__ __forceinline__ double warp_red(double v) {
#pragma unroll
  for (int o = 32; o > 0; o >>= 1) v += __shfl_down(v, o, 64);
  return v;
}

__device__ __forceinline__ void block_acc1(double a, double* acc) {
  __shared__ double s[4];
  const int lane = threadIdx.x & 63, wid = threadIdx.x >> 6;
  a = warp_red(a);
  if (lane == 0) s[wid] = a;
  __syncthreads();
  if (threadIdx.x == 0) atomicAdd(acc, s[0] + s[1] + s[2] + s[3]);
}

__device__ __forceinline__ void block_acc3(double a, double b, double c, double* acc) {
  __shared__ double s[3][4];
  const int lane = threadIdx.x & 63, wid = threadIdx.x >> 6;
  a = warp_red(a); b = warp_red(b); c = warp_red(c);
  if (lane == 0) { s[0][wid] = a; s[1][wid] = b; s[2][wid] = c; }
  __syncthreads();
  if (threadIdx.x == 0) {
    atomicAdd(&acc[0], s[0][0] + s[0][1] + s[0][2] + s[0][3]);
    atomicAdd(&acc[1], s[1][0] + s[1][1] + s[1][2] + s[1][3]);
    atomicAdd(&acc[2], s[2][0] + s[2][1] + s[2][2] + s[2][3]);
  }
}

// Pack gather-source channels: S[v] = {n0,n1,n2,imgA | labA,imgB,labB,0}
__global__ void __launch_bounds__(256) k_pack(
    const float* __restrict__ noise, const float* __restrict__ imgA,
    const float* __restrict__ labA, const float* __restrict__ imgB,
    const float* __restrict__ labB, float4* __restrict__ S) {
  const int v = blockIdx.x * 256 + threadIdx.x;
  float4 a, b;
  a.x = noise[v]; a.y = noise[NVOX + v]; a.z = noise[2*NVOX + v]; a.w = imgA[v];
  b.x = labA[v];  b.y = imgB[v];         b.z = labB[v];           b.w = 0.0f;
  S[2*v] = a; S[2*v + 1] = b;
}

// Per-axis corner prep: clamped coords, weights (0 if invalid).
struct AxisPrep {
  int c0, c1;      // clamped coords
  float w0, w1;    // weights (zeroed if invalid)
};
__device__ __forceinline__ AxisPrep axis_prep(float p) {
  AxisPrep r;
  const float pf = floorf(p);
  const int i0 = (int)pf;
  const float f = p - pf;
  const bool v0 = (i0 >= 0) && (i0 < DSZ);
  const bool v1 = (i0 + 1 >= 0) && (i0 + 1 < DSZ);
  r.c0 = min(max(i0, 0), DSZ - 1);
  r.c1 = min(max(i0 + 1, 0), DSZ - 1);
  r.w0 = v0 ? (1.0f - f) : 0.0f;
  r.w1 = v1 ? f : 0.0f;
  return r;
}

// First warp, both directions (blockIdx.y = dir; 0: phi_AB, 1: phi_BA).
//   W    = warp(Ieps, phi)  -> float4 (x,y,z used)
//   wimg = warp(img,  phi)  -> planar (for LNCC)
//   wl   = warp(lbl,  phi)  -> dice sums vs olbl (reduced only)
__global__ void __launch_bounds__(256) k_warp_first(
    const float* __restrict__ phiAB, const float* __restrict__ phiBA,
    const float4* __restrict__ S,
    const float* __restrict__ labA, const float* __restrict__ labB,
    float4* __restrict__ W1, float4* __restrict__ W2,
    float* __restrict__ wA, float* __restrict__ wB,
    double* __restrict__ acc) {
  const int dir = blockIdx.y;
  const float* __restrict__ phi  = dir ? phiBA : phiAB;
  const float* __restrict__ olbl = dir ? labA  : labB;
  float4* __restrict__ W    = dir ? W2 : W1;
  float*  __restrict__ wimg = dir ? wB : wA;
  double* __restrict__ a    = acc + (dir ? 3 : 0);

  const int v = blockIdx.x * 256 + threadIdx.x;
  const float ob = olbl[v];
  const float z = (phi[v]          + 1.0f) * 0.5f * 127.0f;
  const float y = (phi[NVOX + v]   + 1.0f) * 0.5f * 127.0f;
  const float x = (phi[2*NVOX + v] + 1.0f) * 0.5f * 127.0f;
  const int z0 = (int)floorf(z), y0 = (int)floorf(y), x0 = (int)floorf(x);
  float o0 = 0.f, o1 = 0.f, o2 = 0.f, oi = 0.f, ol = 0.f;
  if (z0 >= -1 && z0 < DSZ && y0 >= -1 && y0 < DSZ && x0 >= -1 && x0 < DSZ) {
    const AxisPrep az = axis_prep(z), ay = axis_prep(y), ax = axis_prep(x);
    const int zc[2] = {az.c0, az.c1}; const float wz[2] = {az.w0, az.w1};
    const int yc[2] = {ay.c0, ay.c1}; const float wy[2] = {ay.w0, ay.w1};
    const int xc[2] = {ax.c0, ax.c1}; const float wx[2] = {ax.w0, ax.w1};

    float4 g0[8], g1[8];
#pragma unroll
    for (int k = 0; k < 8; k++) {
      const int idx = zc[k >> 2] * DD + yc[(k >> 1) & 1] * DSZ + xc[k & 1];
      g0[k] = S[2 * idx];
      g1[k] = S[2 * idx + 1];
    }
#pragma unroll
    for (int k = 0; k < 8; k++) {
      const int iz = zc[k >> 2], iy = yc[(k >> 1) & 1], ix = xc[k & 1];
      const float w = wz[k >> 2] * wy[(k >> 1) & 1] * wx[k & 1];
      const float e0 = (-1.0f + iz * (2.0f/127.0f)) + g0[k].x * (1.0f/128.0f);
      const float e1 = (-1.0f + iy * (2.0f/127.0f)) + g0[k].y * (1.0f/128.0f);
      const float e2 = (-1.0f + ix * (2.0f/127.0f)) + g0[k].z * (1.0f/128.0f);
      o0 += e0 * w; o1 += e1 * w; o2 += e2 * w;
      const float iv = dir ? g1[k].y : g0[k].w;   // imgB : imgA
      const float lv = dir ? g1[k].z : g1[k].x;   // labB : labA
      oi += iv * w;
      ol += lv * w;
    }
  }
  W[v] = make_float4(o0, o1, o2, 0.0f);
  wimg[v] = oi;
  block_acc3((double)(ol * ob), (double)ol, (double)ob, a);
}

// Second warp + MSE, both directions (blockIdx.y = dir).
//   dir 0: fwd = warp(W1, phi_BA) -> acc[6];  dir 1: bwd = warp(W2, phi_AB) -> acc[7]
__global__ void __launch_bounds__(256) k_warp_second_mse(
    const float* __restrict__ phiAB, const float* __restrict__ phiBA,
    const float4* __restrict__ W1, const float4* __restrict__ W2,
    const float* __restrict__ noise, double* __restrict__ acc) {
  const int dir = blockIdx.y;
  const float* __restrict__ phi   = dir ? phiAB : phiBA;
  const float4* __restrict__ Wsrc = dir ? W2 : W1;
  double* __restrict__ a = acc + 6 + dir;

  const int v = blockIdx.x * 256 + threadIdx.x;
  const float z = (phi[v]          + 1.0f) * 0.5f * 127.0f;
  const float y = (phi[NVOX + v]   + 1.0f) * 0.5f * 127.0f;
  const float x = (phi[2*NVOX + v] + 1.0f) * 0.5f * 127.0f;
  const int z0 = (int)floorf(z), y0 = (int)floorf(y), x0 = (int)floorf(x);
  float f0 = 0.f, f1 = 0.f, f2 = 0.f;
  if (z0 >= -1 && z0 < DSZ && y0 >= -1 && y0 < DSZ && x0 >= -1 && x0 < DSZ) {
    const AxisPrep az = axis_prep(z), ay = axis_prep(y), ax = axis_prep(x);
    const int zc[2] = {az.c0, az.c1}; const float wz[2] = {az.w0, az.w1};
    const int yc[2] = {ay.c0, ay.c1}; const float wy[2] = {ay.w0, ay.w1};
    const int xc[2] = {ax.c0, ax.c1}; const float wx[2] = {ax.w0, ax.w1};

    float4 g[8];
#pragma unroll
    for (int k = 0; k < 8; k++) {
      const int idx = zc[k >> 2] * DD + yc[(k >> 1) & 1] * DSZ + xc[k & 1];
      g[k] = Wsrc[idx];
    }
#pragma unroll
    for (int k = 0; k < 8; k++) {
      const float w = wz[k >> 2] * wy[(k >> 1) & 1] * wx[k & 1];
      f0 += g[k].x * w; f1 += g[k].y * w; f2 += g[k].z * w;
    }
  }
  const int zi = v >> 14, yi = (v >> 7) & 127, xi = v & 127;
  const float e0 = (-1.0f + zi * (2.0f/127.0f)) + noise[v]          * (1.0f/128.0f);
  const float e1 = (-1.0f + yi * (2.0f/127.0f)) + noise[NVOX + v]   * (1.0f/128.0f);
  const float e2 = (-1.0f + xi * (2.0f/127.0f)) + noise[2*NVOX + v] * (1.0f/128.0f);
  const float d0 = e0 - f0, d1 = e1 - f1, d2 = e2 - f2;
  block_acc1((double)(d0*d0) + (double)(d1*d1) + (double)(d2*d2), a);
}

// Fully fused LNCC: per block = one z-slice x 8-row y-tile x full x.
// blockIdx.y = pair (0: lncc(wA,imgB) -> acc[8], 1: lncc(imgA,wB) -> acc[9])
__global__ void __launch_bounds__(256) k_lncc(
    const float* __restrict__ wA, const float* __restrict__ imgB,
    const float* __restrict__ imgA, const float* __restrict__ wB,
    double* __restrict__ acc) {
  const int pair = blockIdx.y;
  const float* __restrict__ I = pair ? imgA : wA;
  const float* __restrict__ J = pair ? wB : imgB;
  double* __restrict__ a = acc + 8 + pair;

  const int bx = blockIdx.x;           // 0..2047
  const int zi = bx & 127;
  const int y0 = (bx >> 7) * 8;        // 16 y-tiles

  __shared__ float zb[5][12][128];     // 30 KB
  __shared__ float yb[5][8][128];      // 20 KB
  const int t = threadIdx.x;
  const float K[5] = {KW0, KW1, KW2, KW3, KW4};

  // stage 1: z-blur into LDS (rows y0-2 .. y0+9)
  for (int p = t; p < 12 * 128; p += 256) {
    const int r = p >> 7, x = p & 127;
    const int y = y0 + r - 2;
    float a0 = 0.f, a1 = 0.f, a2 = 0.f, a3 = 0.f, a4 = 0.f;
    if (y >= 0 && y < DSZ) {
      const int base = y * DSZ + x;
#pragma unroll
      for (int s = 0; s < 5; s++) {
        const int zz = zi + s - 2;
        if (zz >= 0 && zz < DSZ) {
          const float iv = I[zz * DD + base], jv = J[zz * DD + base];
          const float k = K[s];
          a0 += k * iv; a1 += k * jv; a2 += k * (iv * jv);
          a3 += k * (iv * iv); a4 += k * (jv * jv);
        }
      }
    }
    zb[0][r][x] = a0; zb[1][r][x] = a1; zb[2][r][x] = a2;
    zb[3][r][x] = a3; zb[4][r][x] = a4;
  }
  __syncthreads();

  // stage 2: y-blur into LDS
  for (int p = t; p < 8 * 128; p += 256) {
    const int r = p >> 7, x = p & 127;
#pragma unroll
    for (int c = 0; c < 5; c++) {
      yb[c][r][x] = KW0 * zb[c][r][x] + KW1 * zb[c][r + 1][x] + KW2 * zb[c][r + 2][x]
                  + KW3 * zb[c][r + 3][x] + KW4 * zb[c][r + 4][x];
    }
  }
  __syncthreads();

  // stage 3: x-blur + LNCC value + reduce
  double lsum = 0.0;
  for (int p = t; p < 8 * 128; p += 256) {
    const int r = p >> 7, x = p & 127;
    float b[5];
#pragma unroll
    for (int c = 0; c < 5; c++) {
      float s = 0.f;
#pragma unroll
      for (int u = 0; u < 5; u++) {
        const int xx = x + u - 2;
        if (xx >= 0 && xx < DSZ) s += K[u] * yb[c][r][xx];
      }
      b[c] = s;
    }
    const float cross = b[2] - b[0] * b[1];
    const float varI = fmaxf(b[3] - b[0] * b[0], 0.0f) + EPSF;
    const float varJ = fmaxf(b[4] - b[1] * b[1], 0.0f) + EPSF;
    lsum += (double)(1.0f - cross / sqrtf(varI * varJ));
  }
  block_acc1(lsum, a);
}

// acc: [0..2]=dice AB (inter, sum wlA, sum labB), [3..5]=dice BA
//      [6]=mse fwd, [7]=mse bwd, [8]=lncc1, [9]=lncc2
__global__ void k_final(const double* __restrict__ acc, float* __restrict__ out) {
  const double n1 = (double)NVOX;
  const double n3 = 3.0 * n1;
  const double ic  = acc[6] / n3 + acc[7] / n3;
  const double sim = acc[8] / n1 + acc[9] / n1;
  const double dA = (2.0 * acc[0] + 1e-5) / (acc[1] + acc[2] + 1e-5);
  const double dB = (2.0 * acc[3] + 1e-5) / (acc[4] + acc[5] + 1e-5);
  out[0] = (float)(128.0 * ic + sim + (1.0 - dA) + (1.0 - dB));
}

extern "C" void kernel_launch(void* const* d_in, const int* in_sizes, int n_in,
                              void* d_out, int out_size, void* d_ws, size_t ws_size,
                              hipStream_t stream) {
  (void)in_sizes; (void)n_in; (void)out_size; (void)ws_size;
  const float* phiAB = (const float*)d_in[0];
  const float* phiBA = (const float*)d_in[1];
  const float* imgA  = (const float*)d_in[2];
  const float* imgB  = (const float*)d_in[3];
  const float* labA  = (const float*)d_in[4];
  const float* labB  = (const float*)d_in[5];
  const float* noise = (const float*)d_in[6];
  float* out = (float*)d_out;

  char* ws = (char*)d_ws;
  double* acc = (double*)ws;                    // 256 B reserved
  float4* S  = (float4*)(ws + 256);             // 2*NVOX float4 = 64 MB
  float4* W1 = S + 2 * (size_t)NVOX;            // NVOX float4 = 32 MB
  float4* W2 = W1 + (size_t)NVOX;               // 32 MB
  float*  wA = (float*)(W2 + (size_t)NVOX);     // 8 MB
  float*  wB = wA + NVOX;                       // 8 MB
  // total: 256 B + 144 MB

  hipMemsetAsync(acc, 0, 16 * sizeof(double), stream);

  k_pack<<<NBLK, 256, 0, stream>>>(noise, imgA, labA, imgB, labB, S);

  k_warp_first<<<dim3(NBLK, 2), 256, 0, stream>>>(
      phiAB, phiBA, S, labA, labB, W1, W2, wA, wB, acc);

  k_warp_second_mse<<<dim3(NBLK, 2), 256, 0, stream>>>(
      phiAB, phiBA, W1, W2, noise, acc);

  k_lncc<<<dim3(2048, 2), 256, 0, stream>>>(wA, imgB, imgA, wB, acc);

  k_final<<<1, 1, 0, stream>>>(acc, out);
}

// Round 11
// 487.269 us; speedup vs baseline: 2.2099x; 2.1620x over previous
//
#include <hip/hip_runtime.h>

// ICON loss (registration), D=128 f32 volumes -> scalar f32.
// R10: REMOVE the single-cache-line f64 atomicAdd hotspot (49k device-scope
// atomics from 16k blocks onto one 64B line — ~30 cy/op serialized ≈ the
// entire 613 µs of k_warp_first; round2 vs R3 identical-time despite opposite
// load structures pinned the bottleneck here, not in the gathers).
// Blocks now write per-block partials to d_ws; k_reduce sums them.

#define DSZ 128
#define DD  (DSZ*DSZ)          // 16384
#define NVOX (DSZ*DSZ*DSZ)     // 2097152
#define NBLK (NVOX/256)        // 8192
#define EPSF 1e-5f

// Gaussian kernel, sigma=1, ksize=5
#define KW0 0.054488684549642945f
#define KW1 0.24420134200323337f
#define KW2 0.40261994689424736f
#define KW3 0.24420134200323337f
#define KW4 0.054488684549642945f

// Partial-sum table: P[counter][0..8191], counter:
//  0..2 dice AB (inter, sum wlA, sum labB)   [8192 slots]
//  3..5 dice BA                               [8192 slots]
//  6..7 mse fwd/bwd                           [8192 slots]
//  8..9 lncc pair0/pair1                      [2048 slots]
#define PSTRIDE 8192

__device__ __forceinline__ double warp_red(double v) {
#pragma unroll
  for (int o = 32; o > 0; o >>= 1) v += __shfl_down(v, o, 64);
  return v;
}

// block-reduce -> ONE partial slot per block (no atomics)
__device__ __forceinline__ void block_part1(double a, double* p) {
  __shared__ double s[4];
  const int lane = threadIdx.x & 63, wid = threadIdx.x >> 6;
  a = warp_red(a);
  if (lane == 0) s[wid] = a;
  __syncthreads();
  if (threadIdx.x == 0) p[blockIdx.x] = s[0] + s[1] + s[2] + s[3];
}

__device__ __forceinline__ void block_part3(double a, double b, double c,
                                            double* p0, double* p1, double* p2) {
  __shared__ double s[3][4];
  const int lane = threadIdx.x & 63, wid = threadIdx.x >> 6;
  a = warp_red(a); b = warp_red(b); c = warp_red(c);
  if (lane == 0) { s[0][wid] = a; s[1][wid] = b; s[2][wid] = c; }
  __syncthreads();
  if (threadIdx.x == 0) {
    p0[blockIdx.x] = s[0][0] + s[0][1] + s[0][2] + s[0][3];
    p1[blockIdx.x] = s[1][0] + s[1][1] + s[1][2] + s[1][3];
    p2[blockIdx.x] = s[2][0] + s[2][1] + s[2][2] + s[2][3];
  }
}

// Pack gather-source channels: S[v] = {n0,n1,n2,imgA | labA,imgB,labB,0}
__global__ void __launch_bounds__(256) k_pack(
    const float* __restrict__ noise, const float* __restrict__ imgA,
    const float* __restrict__ labA, const float* __restrict__ imgB,
    const float* __restrict__ labB, float4* __restrict__ S) {
  const int v = blockIdx.x * 256 + threadIdx.x;
  float4 a, b;
  a.x = noise[v]; a.y = noise[NVOX + v]; a.z = noise[2*NVOX + v]; a.w = imgA[v];
  b.x = labA[v];  b.y = imgB[v];         b.z = labB[v];           b.w = 0.0f;
  S[2*v] = a; S[2*v + 1] = b;
}

// Per-axis corner prep: clamped coords, weights (0 if invalid).
struct AxisPrep {
  int c0, c1;      // clamped coords
  float w0, w1;    // weights (zeroed if invalid)
};
__device__ __forceinline__ AxisPrep axis_prep(float p) {
  AxisPrep r;
  const float pf = floorf(p);
  const int i0 = (int)pf;
  const float f = p - pf;
  const bool v0 = (i0 >= 0) && (i0 < DSZ);
  const bool v1 = (i0 + 1 >= 0) && (i0 + 1 < DSZ);
  r.c0 = min(max(i0, 0), DSZ - 1);
  r.c1 = min(max(i0 + 1, 0), DSZ - 1);
  r.w0 = v0 ? (1.0f - f) : 0.0f;
  r.w1 = v1 ? f : 0.0f;
  return r;
}

// First warp, both directions (blockIdx.y = dir; 0: phi_AB, 1: phi_BA).
__global__ void __launch_bounds__(256) k_warp_first(
    const float* __restrict__ phiAB, const float* __restrict__ phiBA,
    const float4* __restrict__ S,
    const float* __restrict__ labA, const float* __restrict__ labB,
    float4* __restrict__ W1, float4* __restrict__ W2,
    float* __restrict__ wA, float* __restrict__ wB,
    double* __restrict__ P) {
  const int dir = blockIdx.y;
  const float* __restrict__ phi  = dir ? phiBA : phiAB;
  const float* __restrict__ olbl = dir ? labA  : labB;
  float4* __restrict__ W    = dir ? W2 : W1;
  float*  __restrict__ wimg = dir ? wB : wA;
  double* __restrict__ p    = P + (size_t)(dir ? 3 : 0) * PSTRIDE;

  const int v = blockIdx.x * 256 + threadIdx.x;
  const float ob = olbl[v];
  const float z = (phi[v]          + 1.0f) * 0.5f * 127.0f;
  const float y = (phi[NVOX + v]   + 1.0f) * 0.5f * 127.0f;
  const float x = (phi[2*NVOX + v] + 1.0f) * 0.5f * 127.0f;
  const int z0 = (int)floorf(z), y0 = (int)floorf(y), x0 = (int)floorf(x);
  float o0 = 0.f, o1 = 0.f, o2 = 0.f, oi = 0.f, ol = 0.f;
  if (z0 >= -1 && z0 < DSZ && y0 >= -1 && y0 < DSZ && x0 >= -1 && x0 < DSZ) {
    const AxisPrep az = axis_prep(z), ay = axis_prep(y), ax = axis_prep(x);
    const int zc[2] = {az.c0, az.c1}; const float wz[2] = {az.w0, az.w1};
    const int yc[2] = {ay.c0, ay.c1}; const float wy[2] = {ay.w0, ay.w1};
    const int xc[2] = {ax.c0, ax.c1}; const float wx[2] = {ax.w0, ax.w1};

    float4 g0[8], g1[8];
#pragma unroll
    for (int k = 0; k < 8; k++) {
      const int idx = zc[k >> 2] * DD + yc[(k >> 1) & 1] * DSZ + xc[k & 1];
      g0[k] = S[2 * idx];
      g1[k] = S[2 * idx + 1];
    }
#pragma unroll
    for (int k = 0; k < 8; k++) {
      const int iz = zc[k >> 2], iy = yc[(k >> 1) & 1], ix = xc[k & 1];
      const float w = wz[k >> 2] * wy[(k >> 1) & 1] * wx[k & 1];
      const float e0 = (-1.0f + iz * (2.0f/127.0f)) + g0[k].x * (1.0f/128.0f);
      const float e1 = (-1.0f + iy * (2.0f/127.0f)) + g0[k].y * (1.0f/128.0f);
      const float e2 = (-1.0f + ix * (2.0f/127.0f)) + g0[k].z * (1.0f/128.0f);
      o0 += e0 * w; o1 += e1 * w; o2 += e2 * w;
      const float iv = dir ? g1[k].y : g0[k].w;   // imgB : imgA
      const float lv = dir ? g1[k].z : g1[k].x;   // labB : labA
      oi += iv * w;
      ol += lv * w;
    }
  }
  W[v] = make_float4(o0, o1, o2, 0.0f);
  wimg[v] = oi;
  block_part3((double)(ol * ob), (double)ol, (double)ob,
              p, p + PSTRIDE, p + 2 * PSTRIDE);
}

// Second warp + MSE, both directions (blockIdx.y = dir).
__global__ void __launch_bounds__(256) k_warp_second_mse(
    const float* __restrict__ phiAB, const float* __restrict__ phiBA,
    const float4* __restrict__ W1, const float4* __restrict__ W2,
    const float* __restrict__ noise, double* __restrict__ P) {
  const int dir = blockIdx.y;
  const float* __restrict__ phi   = dir ? phiAB : phiBA;
  const float4* __restrict__ Wsrc = dir ? W2 : W1;
  double* __restrict__ p = P + (size_t)(6 + dir) * PSTRIDE;

  const int v = blockIdx.x * 256 + threadIdx.x;
  const float z = (phi[v]          + 1.0f) * 0.5f * 127.0f;
  const float y = (phi[NVOX + v]   + 1.0f) * 0.5f * 127.0f;
  const float x = (phi[2*NVOX + v] + 1.0f) * 0.5f * 127.0f;
  const int z0 = (int)floorf(z), y0 = (int)floorf(y), x0 = (int)floorf(x);
  float f0 = 0.f, f1 = 0.f, f2 = 0.f;
  if (z0 >= -1 && z0 < DSZ && y0 >= -1 && y0 < DSZ && x0 >= -1 && x0 < DSZ) {
    const AxisPrep az = axis_prep(z), ay = axis_prep(y), ax = axis_prep(x);
    const int zc[2] = {az.c0, az.c1}; const float wz[2] = {az.w0, az.w1};
    const int yc[2] = {ay.c0, ay.c1}; const float wy[2] = {ay.w0, ay.w1};
    const int xc[2] = {ax.c0, ax.c1}; const float wx[2] = {ax.w0, ax.w1};

    float4 g[8];
#pragma unroll
    for (int k = 0; k < 8; k++) {
      const int idx = zc[k >> 2] * DD + yc[(k >> 1) & 1] * DSZ + xc[k & 1];
      g[k] = Wsrc[idx];
    }
#pragma unroll
    for (int k = 0; k < 8; k++) {
      const float w = wz[k >> 2] * wy[(k >> 1) & 1] * wx[k & 1];
      f0 += g[k].x * w; f1 += g[k].y * w; f2 += g[k].z * w;
    }
  }
  const int zi = v >> 14, yi = (v >> 7) & 127, xi = v & 127;
  const float e0 = (-1.0f + zi * (2.0f/127.0f)) + noise[v]          * (1.0f/128.0f);
  const float e1 = (-1.0f + yi * (2.0f/127.0f)) + noise[NVOX + v]   * (1.0f/128.0f);
  const float e2 = (-1.0f + xi * (2.0f/127.0f)) + noise[2*NVOX + v] * (1.0f/128.0f);
  const float d0 = e0 - f0, d1 = e1 - f1, d2 = e2 - f2;
  block_part1((double)(d0*d0) + (double)(d1*d1) + (double)(d2*d2), p);
}

// Fully fused LNCC: per block = one z-slice x 8-row y-tile x full x.
// blockIdx.y = pair (0: lncc(wA,imgB) -> counter 8, 1: lncc(imgA,wB) -> 9)
__global__ void __launch_bounds__(256) k_lncc(
    const float* __restrict__ wA, const float* __restrict__ imgB,
    const float* __restrict__ imgA, const float* __restrict__ wB,
    double* __restrict__ P) {
  const int pair = blockIdx.y;
  const float* __restrict__ I = pair ? imgA : wA;
  const float* __restrict__ J = pair ? wB : imgB;
  double* __restrict__ p = P + (size_t)(8 + pair) * PSTRIDE;

  const int bx = blockIdx.x;           // 0..2047
  const int zi = bx & 127;
  const int y0 = (bx >> 7) * 8;        // 16 y-tiles

  __shared__ float zb[5][12][128];     // 30 KB
  __shared__ float yb[5][8][128];      // 20 KB
  const int t = threadIdx.x;
  const float K[5] = {KW0, KW1, KW2, KW3, KW4};

  // stage 1: z-blur into LDS (rows y0-2 .. y0+9)
  for (int pp = t; pp < 12 * 128; pp += 256) {
    const int r = pp >> 7, x = pp & 127;
    const int y = y0 + r - 2;
    float a0 = 0.f, a1 = 0.f, a2 = 0.f, a3 = 0.f, a4 = 0.f;
    if (y >= 0 && y < DSZ) {
      const int base = y * DSZ + x;
#pragma unroll
      for (int s = 0; s < 5; s++) {
        const int zz = zi + s - 2;
        if (zz >= 0 && zz < DSZ) {
          const float iv = I[zz * DD + base], jv = J[zz * DD + base];
          const float k = K[s];
          a0 += k * iv; a1 += k * jv; a2 += k * (iv * jv);
          a3 += k * (iv * iv); a4 += k * (jv * jv);
        }
      }
    }
    zb[0][r][x] = a0; zb[1][r][x] = a1; zb[2][r][x] = a2;
    zb[3][r][x] = a3; zb[4][r][x] = a4;
  }
  __syncthreads();

  // stage 2: y-blur into LDS
  for (int pp = t; pp < 8 * 128; pp += 256) {
    const int r = pp >> 7, x = pp & 127;
#pragma unroll
    for (int c = 0; c < 5; c++) {
      yb[c][r][x] = KW0 * zb[c][r][x] + KW1 * zb[c][r + 1][x] + KW2 * zb[c][r + 2][x]
                  + KW3 * zb[c][r + 3][x] + KW4 * zb[c][r + 4][x];
    }
  }
  __syncthreads();

  // stage 3: x-blur + LNCC value + reduce
  double lsum = 0.0;
  for (int pp = t; pp < 8 * 128; pp += 256) {
    const int r = pp >> 7, x = pp & 127;
    float b[5];
#pragma unroll
    for (int c = 0; c < 5; c++) {
      float s = 0.f;
#pragma unroll
      for (int u = 0; u < 5; u++) {
        const int xx = x + u - 2;
        if (xx >= 0 && xx < DSZ) s += K[u] * yb[c][r][xx];
      }
      b[c] = s;
    }
    const float cross = b[2] - b[0] * b[1];
    const float varI = fmaxf(b[3] - b[0] * b[0], 0.0f) + EPSF;
    const float varJ = fmaxf(b[4] - b[1] * b[1], 0.0f) + EPSF;
    lsum += (double)(1.0f - cross / sqrtf(varI * varJ));
  }
  block_part1(lsum, p);
}

// Sum partial arrays -> acc[0..9]. One block per counter.
__global__ void __launch_bounds__(256) k_reduce(
    const double* __restrict__ P, double* __restrict__ acc) {
  const int c = blockIdx.x;
  const int n = (c >= 8) ? 2048 : 8192;
  const double* src = P + (size_t)c * PSTRIDE;
  double s = 0.0;
  for (int i = threadIdx.x; i < n; i += 256) s += src[i];
  __shared__ double sh[4];
  const int lane = threadIdx.x & 63, wid = threadIdx.x >> 6;
  s = warp_red(s);
  if (lane == 0) sh[wid] = s;
  __syncthreads();
  if (threadIdx.x == 0) acc[c] = sh[0] + sh[1] + sh[2] + sh[3];
}

// acc: [0..2]=dice AB (inter, sum wlA, sum labB), [3..5]=dice BA
//      [6]=mse fwd, [7]=mse bwd, [8]=lncc1, [9]=lncc2
__global__ void k_final(const double* __restrict__ acc, float* __restrict__ out) {
  const double n1 = (double)NVOX;
  const double n3 = 3.0 * n1;
  const double ic  = acc[6] / n3 + acc[7] / n3;
  const double sim = acc[8] / n1 + acc[9] / n1;
  const double dA = (2.0 * acc[0] + 1e-5) / (acc[1] + acc[2] + 1e-5);
  const double dB = (2.0 * acc[3] + 1e-5) / (acc[4] + acc[5] + 1e-5);
  out[0] = (float)(128.0 * ic + sim + (1.0 - dA) + (1.0 - dB));
}

extern "C" void kernel_launch(void* const* d_in, const int* in_sizes, int n_in,
                              void* d_out, int out_size, void* d_ws, size_t ws_size,
                              hipStream_t stream) {
  (void)in_sizes; (void)n_in; (void)out_size; (void)ws_size;
  const float* phiAB = (const float*)d_in[0];
  const float* phiBA = (const float*)d_in[1];
  const float* imgA  = (const float*)d_in[2];
  const float* imgB  = (const float*)d_in[3];
  const float* labA  = (const float*)d_in[4];
  const float* labB  = (const float*)d_in[5];
  const float* noise = (const float*)d_in[6];
  float* out = (float*)d_out;

  char* ws = (char*)d_ws;
  double* acc = (double*)ws;                    // 16 doubles
  double* P   = acc + 16;                       // 10*8192 doubles = 640 KB
  float4* S  = (float4*)(ws + (1 << 20));       // 1 MB offset; 2*NVOX float4 = 64 MB
  float4* W1 = S + 2 * (size_t)NVOX;            // 32 MB
  float4* W2 = W1 + (size_t)NVOX;               // 32 MB
  float*  wA = (float*)(W2 + (size_t)NVOX);     // 8 MB
  float*  wB = wA + NVOX;                       // 8 MB
  // total: 1 MB + 144 MB

  k_pack<<<NBLK, 256, 0, stream>>>(noise, imgA, labA, imgB, labB, S);

  k_warp_first<<<dim3(NBLK, 2), 256, 0, stream>>>(
      phiAB, phiBA, S, labA, labB, W1, W2, wA, wB, P);

  k_warp_second_mse<<<dim3(NBLK, 2), 256, 0, stream>>>(
      phiAB, phiBA, W1, W2, noise, P);

  k_lncc<<<dim3(2048, 2), 256, 0, stream>>>(wA, imgB, imgA, wB, P);

  k_reduce<<<10, 256, 0, stream>>>(P, acc);

  k_final<<<1, 1, 0, stream>>>(acc, out);
}

// Round 13
// 419.282 us; speedup vs baseline: 2.5683x; 1.1621x over previous
//
#include <hip/hip_runtime.h>

// ICON loss (registration), D=128 f32 volumes -> scalar f32.
// R11 (resubmit; round-12 bench was an infra timeout — fusion never measured):
// fuse k_warp_second_mse + k_lncc into ONE dispatch (k_phase2) with
// interleaved block roles (2 gather : 1 lncc) so the latency-bound scattered
// gathers co-reside with the LDS/VALU-bound blur on every CU. Lncc tile
// shrunk to 4 y-rows (LDS 30 KB) so gather-role occupancy stays 20 waves/CU.
// R10's atomic->partials fix retained (613->145 us on k_warp_first).

#define DSZ 128
#define DD  (DSZ*DSZ)          // 16384
#define NVOX (DSZ*DSZ*DSZ)     // 2097152
#define NBLK (NVOX/256)        // 8192
#define EPSF 1e-5f

// Gaussian kernel, sigma=1, ksize=5
#define KW0 0.054488684549642945f
#define KW1 0.24420134200323337f
#define KW2 0.40261994689424736f
#define KW3 0.24420134200323337f
#define KW4 0.054488684549642945f

// Partial-sum table: P[counter][slot]
//  0..2 dice AB (8192 slots)   3..5 dice BA (8192)
//  6..7 mse fwd/bwd (8192)     8..9 lncc pair0/1 (4096)
#define PSTRIDE 8192

__device__ __forceinline__ double warp_red(double v) {
#pragma unroll
  for (int o = 32; o > 0; o >>= 1) v += __shfl_down(v, o, 64);
  return v;
}

// block-reduce -> one partial slot (explicit slot index; no atomics)
__device__ __forceinline__ void block_part1(double a, double* p, int slot) {
  __shared__ double s1[4];
  const int lane = threadIdx.x & 63, wid = threadIdx.x >> 6;
  a = warp_red(a);
  if (lane == 0) s1[wid] = a;
  __syncthreads();
  if (threadIdx.x == 0) p[slot] = s1[0] + s1[1] + s1[2] + s1[3];
}

__device__ __forceinline__ void block_part3(double a, double b, double c,
                                            double* p0, double* p1, double* p2,
                                            int slot) {
  __shared__ double s3[3][4];
  const int lane = threadIdx.x & 63, wid = threadIdx.x >> 6;
  a = warp_red(a); b = warp_red(b); c = warp_red(c);
  if (lane == 0) { s3[0][wid] = a; s3[1][wid] = b; s3[2][wid] = c; }
  __syncthreads();
  if (threadIdx.x == 0) {
    p0[slot] = s3[0][0] + s3[0][1] + s3[0][2] + s3[0][3];
    p1[slot] = s3[1][0] + s3[1][1] + s3[1][2] + s3[1][3];
    p2[slot] = s3[2][0] + s3[2][1] + s3[2][2] + s3[2][3];
  }
}

// Pack gather-source channels: S[v] = {n0,n1,n2,imgA | labA,imgB,labB,0}
__global__ void __launch_bounds__(256) k_pack(
    const float* __restrict__ noise, const float* __restrict__ imgA,
    const float* __restrict__ labA, const float* __restrict__ imgB,
    const float* __restrict__ labB, float4* __restrict__ S) {
  const int v = blockIdx.x * 256 + threadIdx.x;
  float4 a, b;
  a.x = noise[v]; a.y = noise[NVOX + v]; a.z = noise[2*NVOX + v]; a.w = imgA[v];
  b.x = labA[v];  b.y = imgB[v];         b.z = labB[v];           b.w = 0.0f;
  S[2*v] = a; S[2*v + 1] = b;
}

// Per-axis corner prep: clamped coords, weights (0 if invalid).
struct AxisPrep {
  int c0, c1;
  float w0, w1;
};
__device__ __forceinline__ AxisPrep axis_prep(float p) {
  AxisPrep r;
  const float pf = floorf(p);
  const int i0 = (int)pf;
  const float f = p - pf;
  const bool v0 = (i0 >= 0) && (i0 < DSZ);
  const bool v1 = (i0 + 1 >= 0) && (i0 + 1 < DSZ);
  r.c0 = min(max(i0, 0), DSZ - 1);
  r.c1 = min(max(i0 + 1, 0), DSZ - 1);
  r.w0 = v0 ? (1.0f - f) : 0.0f;
  r.w1 = v1 ? f : 0.0f;
  return r;
}

// First warp, both directions (blockIdx.y = dir). Unchanged from R10 (control).
__global__ void __launch_bounds__(256) k_warp_first(
    const float* __restrict__ phiAB, const float* __restrict__ phiBA,
    const float4* __restrict__ S,
    const float* __restrict__ labA, const float* __restrict__ labB,
    float4* __restrict__ W1, float4* __restrict__ W2,
    float* __restrict__ wA, float* __restrict__ wB,
    double* __restrict__ P) {
  const int dir = blockIdx.y;
  const float* __restrict__ phi  = dir ? phiBA : phiAB;
  const float* __restrict__ olbl = dir ? labA  : labB;
  float4* __restrict__ W    = dir ? W2 : W1;
  float*  __restrict__ wimg = dir ? wB : wA;
  double* __restrict__ p    = P + (size_t)(dir ? 3 : 0) * PSTRIDE;

  const int v = blockIdx.x * 256 + threadIdx.x;
  const float ob = olbl[v];
  const float z = (phi[v]          + 1.0f) * 0.5f * 127.0f;
  const float y = (phi[NVOX + v]   + 1.0f) * 0.5f * 127.0f;
  const float x = (phi[2*NVOX + v] + 1.0f) * 0.5f * 127.0f;
  const int z0 = (int)floorf(z), y0 = (int)floorf(y), x0 = (int)floorf(x);
  float o0 = 0.f, o1 = 0.f, o2 = 0.f, oi = 0.f, ol = 0.f;
  if (z0 >= -1 && z0 < DSZ && y0 >= -1 && y0 < DSZ && x0 >= -1 && x0 < DSZ) {
    const AxisPrep az = axis_prep(z), ay = axis_prep(y), ax = axis_prep(x);
    const int zc[2] = {az.c0, az.c1}; const float wz[2] = {az.w0, az.w1};
    const int yc[2] = {ay.c0, ay.c1}; const float wy[2] = {ay.w0, ay.w1};
    const int xc[2] = {ax.c0, ax.c1}; const float wx[2] = {ax.w0, ax.w1};

    float4 g0[8], g1[8];
#pragma unroll
    for (int k = 0; k < 8; k++) {
      const int idx = zc[k >> 2] * DD + yc[(k >> 1) & 1] * DSZ + xc[k & 1];
      g0[k] = S[2 * idx];
      g1[k] = S[2 * idx + 1];
    }
#pragma unroll
    for (int k = 0; k < 8; k++) {
      const int iz = zc[k >> 2], iy = yc[(k >> 1) & 1], ix = xc[k & 1];
      const float w = wz[k >> 2] * wy[(k >> 1) & 1] * wx[k & 1];
      const float e0 = (-1.0f + iz * (2.0f/127.0f)) + g0[k].x * (1.0f/128.0f);
      const float e1 = (-1.0f + iy * (2.0f/127.0f)) + g0[k].y * (1.0f/128.0f);
      const float e2 = (-1.0f + ix * (2.0f/127.0f)) + g0[k].z * (1.0f/128.0f);
      o0 += e0 * w; o1 += e1 * w; o2 += e2 * w;
      const float iv = dir ? g1[k].y : g0[k].w;   // imgB : imgA
      const float lv = dir ? g1[k].z : g1[k].x;   // labB : labA
      oi += iv * w;
      ol += lv * w;
    }
  }
  W[v] = make_float4(o0, o1, o2, 0.0f);
  wimg[v] = oi;
  block_part3((double)(ol * ob), (double)ol, (double)ob,
              p, p + PSTRIDE, p + 2 * PSTRIDE, blockIdx.x);
}

// Phase 2 fused: interleaved roles. Group of 3 blocks = 2 gather (mse) + 1 lncc.
// gather: gid 0..16383 -> dir = gid>>13, vb = gid&8191 -> counters 6/7
// lncc:   lid 0..8191  -> pair = lid>>12, bx = lid&4095 (z = bx&127, ytile = bx>>7)
//         4-row y-tile, LDS 30 KB -> 5 blocks/CU keeps gather occupancy at 20 waves.
__global__ void __launch_bounds__(256) k_phase2(
    const float* __restrict__ phiAB, const float* __restrict__ phiBA,
    const float4* __restrict__ W1, const float4* __restrict__ W2,
    const float* __restrict__ noise,
    const float* __restrict__ wA, const float* __restrict__ imgB,
    const float* __restrict__ imgA, const float* __restrict__ wB,
    double* __restrict__ P) {
  __shared__ float zb[5][8][128];      // 20 KB
  __shared__ float yb[5][4][128];      // 10 KB
  const int bid = blockIdx.x;
  const int grp = bid / 3, rem = bid - grp * 3;

  if (rem < 2) {
    // ---- gather role: second warp + MSE ----
    const int gid = grp * 2 + rem;          // 0..16383
    const int dir = gid >> 13;
    const int vb  = gid & 8191;
    const float* __restrict__ phi   = dir ? phiAB : phiBA;
    const float4* __restrict__ Wsrc = dir ? W2 : W1;
    double* __restrict__ p = P + (size_t)(6 + dir) * PSTRIDE;

    const int v = vb * 256 + threadIdx.x;
    const float z = (phi[v]          + 1.0f) * 0.5f * 127.0f;
    const float y = (phi[NVOX + v]   + 1.0f) * 0.5f * 127.0f;
    const float x = (phi[2*NVOX + v] + 1.0f) * 0.5f * 127.0f;
    const int z0 = (int)floorf(z), y0 = (int)floorf(y), x0 = (int)floorf(x);
    float f0 = 0.f, f1 = 0.f, f2 = 0.f;
    if (z0 >= -1 && z0 < DSZ && y0 >= -1 && y0 < DSZ && x0 >= -1 && x0 < DSZ) {
      const AxisPrep az = axis_prep(z), ay = axis_prep(y), ax = axis_prep(x);
      const int zc[2] = {az.c0, az.c1}; const float wz[2] = {az.w0, az.w1};
      const int yc[2] = {ay.c0, ay.c1}; const float wy[2] = {ay.w0, ay.w1};
      const int xc[2] = {ax.c0, ax.c1}; const float wx[2] = {ax.w0, ax.w1};

      float4 g[8];
#pragma unroll
      for (int k = 0; k < 8; k++) {
        const int idx = zc[k >> 2] * DD + yc[(k >> 1) & 1] * DSZ + xc[k & 1];
        g[k] = Wsrc[idx];
      }
#pragma unroll
      for (int k = 0; k < 8; k++) {
        const float w = wz[k >> 2] * wy[(k >> 1) & 1] * wx[k & 1];
        f0 += g[k].x * w; f1 += g[k].y * w; f2 += g[k].z * w;
      }
    }
    const int zi = v >> 14, yi = (v >> 7) & 127, xi = v & 127;
    const float e0 = (-1.0f + zi * (2.0f/127.0f)) + noise[v]          * (1.0f/128.0f);
    const float e1 = (-1.0f + yi * (2.0f/127.0f)) + noise[NVOX + v]   * (1.0f/128.0f);
    const float e2 = (-1.0f + xi * (2.0f/127.0f)) + noise[2*NVOX + v] * (1.0f/128.0f);
    const float d0 = e0 - f0, d1 = e1 - f1, d2 = e2 - f2;
    block_part1((double)(d0*d0) + (double)(d1*d1) + (double)(d2*d2), p, vb);
  } else {
    // ---- lncc role: fused separable blur + reduction, 4-row y-tile ----
    const int lid = grp;                    // 0..8191
    const int pair = lid >> 12;
    const int bx   = lid & 4095;
    const float* __restrict__ I = pair ? imgA : wA;
    const float* __restrict__ J = pair ? wB : imgB;
    double* __restrict__ p = P + (size_t)(8 + pair) * PSTRIDE;

    const int zi = bx & 127;
    const int y0 = (bx >> 7) * 4;           // 32 y-tiles of 4 rows
    const int t = threadIdx.x;
    const float K[5] = {KW0, KW1, KW2, KW3, KW4};

    // stage 1: z-blur into LDS (rows y0-2 .. y0+5)
    for (int pp = t; pp < 8 * 128; pp += 256) {
      const int r = pp >> 7, x = pp & 127;
      const int y = y0 + r - 2;
      float a0 = 0.f, a1 = 0.f, a2 = 0.f, a3 = 0.f, a4 = 0.f;
      if (y >= 0 && y < DSZ) {
        const int base = y * DSZ + x;
#pragma unroll
        for (int s = 0; s < 5; s++) {
          const int zz = zi + s - 2;
          if (zz >= 0 && zz < DSZ) {
            const float iv = I[zz * DD + base], jv = J[zz * DD + base];
            const float k = K[s];
            a0 += k * iv; a1 += k * jv; a2 += k * (iv * jv);
            a3 += k * (iv * iv); a4 += k * (jv * jv);
          }
        }
      }
      zb[0][r][x] = a0; zb[1][r][x] = a1; zb[2][r][x] = a2;
      zb[3][r][x] = a3; zb[4][r][x] = a4;
    }
    __syncthreads();

    // stage 2: y-blur into LDS
    for (int pp = t; pp < 4 * 128; pp += 256) {
      const int r = pp >> 7, x = pp & 127;
#pragma unroll
      for (int c = 0; c < 5; c++) {
        yb[c][r][x] = KW0 * zb[c][r][x] + KW1 * zb[c][r + 1][x] + KW2 * zb[c][r + 2][x]
                    + KW3 * zb[c][r + 3][x] + KW4 * zb[c][r + 4][x];
      }
    }
    __syncthreads();

    // stage 3: x-blur + LNCC value + reduce
    double lsum = 0.0;
    for (int pp = t; pp < 4 * 128; pp += 256) {
      const int r = pp >> 7, x = pp & 127;
      float b[5];
#pragma unroll
      for (int c = 0; c < 5; c++) {
        float s = 0.f;
#pragma unroll
        for (int u = 0; u < 5; u++) {
          const int xx = x + u - 2;
          if (xx >= 0 && xx < DSZ) s += K[u] * yb[c][r][xx];
        }
        b[c] = s;
      }
      const float cross = b[2] - b[0] * b[1];
      const float varI = fmaxf(b[3] - b[0] * b[0], 0.0f) + EPSF;
      const float varJ = fmaxf(b[4] - b[1] * b[1], 0.0f) + EPSF;
      lsum += (double)(1.0f - cross / sqrtf(varI * varJ));
    }
    block_part1(lsum, p, bx);
  }
}

// Sum partial arrays -> acc[0..9]. One block per counter.
__global__ void __launch_bounds__(256) k_reduce(
    const double* __restrict__ P, double* __restrict__ acc) {
  const int c = blockIdx.x;
  const int n = (c >= 8) ? 4096 : 8192;
  const double* src = P + (size_t)c * PSTRIDE;
  double s = 0.0;
  for (int i = threadIdx.x; i < n; i += 256) s += src[i];
  __shared__ double sh[4];
  const int lane = threadIdx.x & 63, wid = threadIdx.x >> 6;
  s = warp_red(s);
  if (lane == 0) sh[wid] = s;
  __syncthreads();
  if (threadIdx.x == 0) acc[c] = sh[0] + sh[1] + sh[2] + sh[3];
}

// acc: [0..2]=dice AB, [3..5]=dice BA, [6]=mse fwd, [7]=mse bwd, [8..9]=lncc
__global__ void k_final(const double* __restrict__ acc, float* __restrict__ out) {
  const double n1 = (double)NVOX;
  const double n3 = 3.0 * n1;
  const double ic  = acc[6] / n3 + acc[7] / n3;
  const double sim = acc[8] / n1 + acc[9] / n1;
  const double dA = (2.0 * acc[0] + 1e-5) / (acc[1] + acc[2] + 1e-5);
  const double dB = (2.0 * acc[3] + 1e-5) / (acc[4] + acc[5] + 1e-5);
  out[0] = (float)(128.0 * ic + sim + (1.0 - dA) + (1.0 - dB));
}

extern "C" void kernel_launch(void* const* d_in, const int* in_sizes, int n_in,
                              void* d_out, int out_size, void* d_ws, size_t ws_size,
                              hipStream_t stream) {
  (void)in_sizes; (void)n_in; (void)out_size; (void)ws_size;
  const float* phiAB = (const float*)d_in[0];
  const float* phiBA = (const float*)d_in[1];
  const float* imgA  = (const float*)d_in[2];
  const float* imgB  = (const float*)d_in[3];
  const float* labA  = (const float*)d_in[4];
  const float* labB  = (const float*)d_in[5];
  const float* noise = (const float*)d_in[6];
  float* out = (float*)d_out;

  char* ws = (char*)d_ws;
  double* acc = (double*)ws;                    // 16 doubles
  double* P   = acc + 16;                       // 10*8192 doubles = 640 KB
  float4* S  = (float4*)(ws + (1 << 20));       // 64 MB
  float4* W1 = S + 2 * (size_t)NVOX;            // 32 MB
  float4* W2 = W1 + (size_t)NVOX;               // 32 MB
  float*  wA = (float*)(W2 + (size_t)NVOX);     // 8 MB
  float*  wB = wA + NVOX;                       // 8 MB
  // total: 1 MB + 144 MB

  k_pack<<<NBLK, 256, 0, stream>>>(noise, imgA, labA, imgB, labB, S);

  k_warp_first<<<dim3(NBLK, 2), 256, 0, stream>>>(
      phiAB, phiBA, S, labA, labB, W1, W2, wA, wB, P);

  // 16384 gather blocks + 8192 lncc blocks, interleaved 2:1
  k_phase2<<<24576, 256, 0, stream>>>(
      phiAB, phiBA, W1, W2, noise, wA, imgB, imgA, wB, P);

  k_reduce<<<10, 256, 0, stream>>>(P, acc);

  k_final<<<1, 1, 0, stream>>>(acc, out);
}